// Round 1
// baseline (887.996 us; speedup 1.0000x reference)
//
#include <hip/hip_runtime.h>

// Problem constants (fixed by the reference's setup_inputs)
#define BB 8
#define LL 4096
#define KK 576
#define DD 4096
#define IMG_TOK 32000
#define IGNORE_IDX -100

#define THREADS 256
#define PER (LL / THREADS)   // 16 tokens per thread in the scan kernel
#define D4 (DD / 4)          // 1024 float4 per token row

// ---------------------------------------------------------------------------
// Kernel 1: per-row scans + all small outputs + per-token gather code.
// code[b*L+l]:  >=0 -> copy image_features[b, code], -1 -> zeros, -2 -> copy
// inputs_embeds[b,l].
// ---------------------------------------------------------------------------
__global__ __launch_bounds__(THREADS)
void meta_kernel(const int* __restrict__ input_ids,
                 const int* __restrict__ attention_mask,
                 const int* __restrict__ labels,
                 int* __restrict__ code,
                 float* __restrict__ out_fam,   // final_attention_mask
                 float* __restrict__ out_lab,   // final_labels
                 float* __restrict__ out_pos,   // position_ids
                 float* __restrict__ out_msk)   // image_token_mask
{
    const int b = blockIdx.x;
    const int t = threadIdx.x;
    const int base = b * LL + t * PER;

    int isimg[PER];
    int local_img = 0;
    #pragma unroll
    for (int i = 0; i < PER; ++i) {
        int im = (input_ids[base + i] == IMG_TOK) ? 1 : 0;
        isimg[i] = im;
        local_img += im;
    }

    __shared__ int s[THREADS];

    // --- scan 1: cumsum(is_img) across the row (Hillis-Steele in LDS) ---
    s[t] = local_img;
    __syncthreads();
    for (int off = 1; off < THREADS; off <<= 1) {
        int v = s[t];
        int w = (t >= off) ? s[t - off] : 0;
        __syncthreads();
        s[t] = v + w;
        __syncthreads();
    }
    int img_excl = s[t] - local_img;   // image tokens strictly before this chunk

    // classify tokens, emit code / fam / labels / image_token_mask
    int fam_local[PER];
    int fam_sum = 0;
    int r = img_excl;
    #pragma unroll
    for (int i = 0; i < PER; ++i) {
        int c, f, msk;
        if (isimg[i]) {
            int rk = r++;
            if (rk < KK) { c = rk; f = 1; msk = 1; }   // write: gets a feature
            else         { c = -1; f = 0; msk = 0; }   // extra: zeroed/padded
        } else {
            c = -2;
            f = attention_mask[base + i];
            msk = 0;
        }
        code[base + i] = c;
        fam_local[i] = f;
        fam_sum += f;
        out_fam[base + i] = (float)f;
        out_msk[base + i] = (float)msk;
        out_lab[base + i] = isimg[i] ? (float)IGNORE_IDX : (float)labels[base + i];
    }

    // --- scan 2: cumsum(final_attention_mask) -> position_ids ---
    __syncthreads();
    s[t] = fam_sum;
    __syncthreads();
    for (int off = 1; off < THREADS; off <<= 1) {
        int v = s[t];
        int w = (t >= off) ? s[t - off] : 0;
        __syncthreads();
        s[t] = v + w;
        __syncthreads();
    }
    int fam_excl = s[t] - fam_sum;
    int cum = fam_excl;
    #pragma unroll
    for (int i = 0; i < PER; ++i) {
        cum += fam_local[i];
        int p = cum - 1;
        if (p < 0) p = 0;
        out_pos[base + i] = (float)p;
    }
}

// ---------------------------------------------------------------------------
// Kernel 2: big gather/copy. One block per (b,l) token row; branch is
// block-uniform; float4 vectorized (16 B/lane).
// ---------------------------------------------------------------------------
__global__ __launch_bounds__(256)
void embed_kernel(const float4* __restrict__ feat,
                  const float4* __restrict__ emb,
                  const int* __restrict__ code,
                  float4* __restrict__ out)
{
    const int row = blockIdx.x;        // 0 .. B*L-1
    const int b = row >> 12;           // L = 4096
    const int c = code[row];
    const int t = threadIdx.x;
    float4* dst = out + (size_t)row * D4;

    if (c == -2) {
        const float4* src = emb + (size_t)row * D4;
        #pragma unroll
        for (int i = 0; i < D4 / 256; ++i)
            dst[t + i * 256] = src[t + i * 256];
    } else if (c >= 0) {
        const float4* src = feat + ((size_t)b * KK + c) * D4;
        #pragma unroll
        for (int i = 0; i < D4 / 256; ++i)
            dst[t + i * 256] = src[t + i * 256];
    } else {
        const float4 z = make_float4(0.f, 0.f, 0.f, 0.f);
        #pragma unroll
        for (int i = 0; i < D4 / 256; ++i)
            dst[t + i * 256] = z;
    }
}

extern "C" void kernel_launch(void* const* d_in, const int* in_sizes, int n_in,
                              void* d_out, int out_size, void* d_ws, size_t ws_size,
                              hipStream_t stream)
{
    const float* feat = (const float*)d_in[0];   // image_features (B,K,D) f32
    const float* emb  = (const float*)d_in[1];   // inputs_embeds  (B,L,D) f32
    const int*   ids  = (const int*)d_in[2];     // input_ids      (B,L)
    const int*   attn = (const int*)d_in[3];     // attention_mask (B,L)
    const int*   lab  = (const int*)d_in[4];     // labels         (B,L)

    float* out = (float*)d_out;
    const size_t embN = (size_t)BB * LL * DD;
    const size_t rowN = (size_t)BB * LL;
    float* out_fam = out + embN;
    float* out_lab = out_fam + rowN;
    float* out_pos = out_lab + rowN;
    float* out_msk = out_pos + rowN;

    int* code = (int*)d_ws;   // B*L ints = 128 KB scratch

    meta_kernel<<<BB, THREADS, 0, stream>>>(ids, attn, lab, code,
                                            out_fam, out_lab, out_pos, out_msk);
    embed_kernel<<<BB * LL, 256, 0, stream>>>((const float4*)feat,
                                              (const float4*)emb,
                                              code, (float4*)out);
}